// Round 4
// baseline (64931.195 us; speedup 1.0000x reference)
//
#include <hip/hip_runtime.h>
#include <math.h>

// Problem constants
#define BB  64
#define TT  512
#define IN  64
#define HH  512
#define ZHH 128
#define NZZ 32
#define NT  1024   // 16 waves; one WG per batch

// bf16 weight buffer layout in d_ws (element offsets, unsigned short)
// U_WH / U_X2H are PACKED in MFMA B-fragment order:
//   P[((nb*16 + kb)*64 + lane)*8 + j] = W[nb*16 + (lane&15)][kb*32 + (lane>>4)*8 + j]
#define U_WH    0          // packed [96 nb][16 kb][64 lane][8 j]
#define U_X2H   786432     // packed [24 nb][16 kb][64 lane][8 j] (cols 0..511)
#define U_X2HC  983040     // row-major [384][64] (cond cols 512..575)
#define U_H2H   1007616    // [384][128]
#define U_WX    1056768    // [1536][64]
#define U_Z     1155072    // [288][128]  (zh||zx||zb)
#define U_D     1191936    // [3 kind][3 l][512 h][32 nz]
#define U_END   1339392
#define CNT_BYTES ((size_t)U_END * 2)   // 512 ints of step counters after weights

typedef __attribute__((ext_vector_type(4))) float floatx4;
typedef __attribute__((ext_vector_type(8))) short shortx8;

__device__ __forceinline__ float sigmoidf_(float x) {
    return 1.0f / (1.0f + __expf(-x));
}

__device__ __forceinline__ float bflo(unsigned u) { return __uint_as_float(u << 16); }
__device__ __forceinline__ float bfhi(unsigned u) { return __uint_as_float(u & 0xffff0000u); }

__device__ __forceinline__ unsigned short f2bf(float f) {
    unsigned u = __float_as_uint(f);
    return (unsigned short)((u + 0x7fffu + ((u >> 16) & 1u)) >> 16);
}

__device__ __forceinline__ float wred(float v) {
    v += __shfl_xor(v, 32, 64);
    v += __shfl_xor(v, 16, 64);
    v += __shfl_xor(v, 8, 64);
    v += __shfl_xor(v, 4, 64);
    v += __shfl_xor(v, 2, 64);
    v += __shfl_xor(v, 1, 64);
    return v;
}

__device__ __forceinline__ float dotbf8(uint4 U, float4 a, float4 b) {
    return bflo(U.x)*a.x + bfhi(U.x)*a.y + bflo(U.y)*a.z + bfhi(U.y)*a.w
         + bflo(U.z)*b.x + bfhi(U.z)*b.y + bflo(U.w)*b.z + bfhi(U.w)*b.w;
}

// ---------- pre-pass: fp32 -> bf16 (RNE) into ws, with MFMA packing ----------
__global__ __launch_bounds__(256)
void conv_bf16(const float* __restrict__ wh, const float* __restrict__ x2h,
               const float* __restrict__ h2h, const float* __restrict__ wx,
               const float* __restrict__ zh, const float* __restrict__ zx,
               const float* __restrict__ zb, const float* __restrict__ dh,
               const float* __restrict__ dx, const float* __restrict__ db,
               unsigned short* __restrict__ o)
{
    int i = blockIdx.x * 256 + threadIdx.x;
    float v;
    if (i < U_X2H) {                       // packed wh
        int idx = i;
        int nb = idx >> 13, kb = (idx >> 9) & 15, lane = (idx >> 3) & 63, j = idx & 7;
        int row = nb*16 + (lane & 15);
        int col = kb*32 + (lane >> 4)*8 + j;
        v = wh[(size_t)row*512 + col];
    } else if (i < U_X2HC) {               // packed x2h (h part)
        int idx = i - U_X2H;
        int nb = idx >> 13, kb = (idx >> 9) & 15, lane = (idx >> 3) & 63, j = idx & 7;
        int row = nb*16 + (lane & 15);
        int col = kb*32 + (lane >> 4)*8 + j;
        v = x2h[(size_t)row*576 + col];
    } else if (i < U_H2H) {                // x2h cond part, row-major
        int idx = i - U_X2HC;
        int r = idx >> 6, c = idx & 63;
        v = x2h[(size_t)r*576 + 512 + c];
    } else if (i < U_WX)   v = h2h[i - U_H2H];
    else if (i < U_Z)      v = wx[i - U_WX];
    else if (i < U_Z + 12288)  v = zh[i - U_Z];
    else if (i < U_Z + 24576)  v = zx[i - U_Z - 12288];
    else if (i < U_D)          v = zb[i - U_Z - 24576];
    else if (i < U_D + 49152)  v = dh[i - U_D];
    else if (i < U_D + 98304)  v = dx[i - U_D - 49152];
    else if (i < U_END)        v = db[i - U_D - 98304];
    else return;
    o[i] = f2bf(v);
}

// ---------- main kernel: one WG per batch, bf16 weights, MFMA for K=512 ----------
__global__ __launch_bounds__(NT, 4)
void hypercell_mfma(
    const float* __restrict__ xs, const float* __restrict__ cond,
    const float* __restrict__ h_c, const float* __restrict__ h_c_hat,
    const float* __restrict__ x2h_b, const float* __restrict__ h2h_b,
    const float* __restrict__ zh_b, const float* __restrict__ zx_b,
    const float* __restrict__ db_b,
    const unsigned short* __restrict__ wbf,
    int* __restrict__ stepcnt,
    float* __restrict__ out)
{
    __shared__ float h_s[HH];
    __shared__ float x_s[IN];
    __shared__ float hhat_s[ZHH];
    __shared__ float whh_s[3*HH];
    __shared__ float wxx_s[3*HH];
    __shared__ float ih_s[3*ZHH];
    __shared__ float hh_s[3*ZHH];
    __shared__ float ihc_s[3*ZHH];   // time-invariant cond part of ih (+bias)
    __shared__ float z_s[288];
    __shared__ __align__(16) unsigned short hbf_s[HH];

    const int b    = blockIdx.x;
    const int tid  = threadIdx.x;
    const int lane = tid & 63;
    const int wv   = tid >> 6;       // 0..15
    const int quad = lane >> 4;      // 0..3

    // ---- init state; stage cond into x_s for the ihc precompute ----
    if (tid < IN) x_s[tid] = cond[(size_t)b*IN + tid];
    if (tid < HH) { float v = h_c[(size_t)b*HH + tid]; h_s[tid] = v; hbf_s[tid] = f2bf(v); }
    if (tid < ZHH) hhat_s[tid] = h_c_hat[(size_t)b*ZHH + tid];
    __syncthreads();

    // ihc[r] = cond . x2h_w[r,512:576] + x2h_b[r]   (time-invariant)
    if (tid < 384) {
        const uint4* w4 = (const uint4*)(wbf + U_X2HC + (size_t)tid*64);
        const float4* c4 = (const float4*)x_s;
        float acc = x2h_b[tid];
        #pragma unroll
        for (int j = 0; j < 8; ++j)
            acc += dotbf8(w4[j], c4[2*j], c4[2*j+1]);
        ihc_s[tid] = acc;
    }
    __syncthreads();

    for (int t = 0; t < TT; ++t) {
        if (tid < IN) x_s[tid] = xs[((size_t)b*TT + t)*IN + tid];
        __syncthreads();   // x_s staged; hbf_s/h_s from prev step visible

        // ===== MFMA: whh (nb 0..95) + ih h-part (nb 96..119) =====
        // A = h replicated over m; packed B: one coalesced 16B/lane load per kb.
        {
            floatx4 acc[8];
            #pragma unroll
            for (int i = 0; i < 8; ++i) acc[i] = (floatx4){0.f, 0.f, 0.f, 0.f};
            for (int kh = 0; kh < 2; ++kh) {
                shortx8 aF[8];
                #pragma unroll
                for (int kb = 0; kb < 8; ++kb)
                    aF[kb] = *(const shortx8*)&hbf_s[kh*256 + kb*32 + quad*8];
                #pragma unroll
                for (int i = 0; i < 8; ++i) {
                    const int nb = wv + 16*i;
                    if (nb < 120) {
                        const unsigned short* wp = (nb < 96)
                            ? wbf + U_WH  + (((size_t)(nb*16 + kh*8))*64 + lane)*8
                            : wbf + U_X2H + (((size_t)((nb-96)*16 + kh*8))*64 + lane)*8;
                        floatx4 a = acc[i];
                        #pragma unroll
                        for (int kb = 0; kb < 8; ++kb) {
                            shortx8 bF = *(const shortx8*)(wp + kb*512);
                            a = __builtin_amdgcn_mfma_f32_16x16x32_bf16(aF[kb], bF, a, 0, 0, 0);
                        }
                        acc[i] = a;
                    }
                }
            }
            #pragma unroll
            for (int i = 0; i < 8; ++i) {
                const int nb = wv + 16*i;
                if (nb < 120 && lane < 16) {
                    float v = acc[i][0];
                    if (nb < 96) whh_s[nb*16 + lane] = v;
                    else { int r = (nb-96)*16 + lane; ih_s[r] = v + ihc_s[r]; }
                }
            }
        }

        // ===== vector hh: 24 rows/wave, K=128 (old hhat) =====
        {
            float2 hv = *(const float2*)&hhat_s[lane*2];
            #pragma unroll 4
            for (int i = 0; i < 24; ++i) {
                int r = wv*24 + i;
                unsigned u = *(const unsigned*)(wbf + U_H2H + (size_t)r*128 + lane*2);
                float p = wred(bflo(u)*hv.x + bfhi(u)*hv.y);
                if (lane == 0) hh_s[r] = p + h2h_b[r];
            }
        }

        // ===== vector wxx: thread-per-row, K=64 =====
        {
            const float4* x4 = (const float4*)x_s;
            {
                const uint4* w4 = (const uint4*)(wbf + U_WX + (size_t)tid*64);
                float acc = 0.f;
                #pragma unroll
                for (int j = 0; j < 8; ++j)
                    acc += dotbf8(w4[j], x4[2*j], x4[2*j+1]);
                wxx_s[tid] = acc;
            }
            if (tid < 512) {
                const int r = 1024 + tid;
                const uint4* w4 = (const uint4*)(wbf + U_WX + (size_t)r*64);
                float acc = 0.f;
                #pragma unroll
                for (int j = 0; j < 8; ++j)
                    acc += dotbf8(w4[j], x4[2*j], x4[2*j+1]);
                wxx_s[r] = acc;
            }
        }
        __syncthreads();   // ih/hh/whh/wxx complete

        // ===== hyper GRU gates -> hhat_new =====
        if (tid < ZHH) {
            const int j = tid;
            float r = sigmoidf_(ih_s[j] + hh_s[j]);
            float g = sigmoidf_(ih_s[ZHH+j] + hh_s[ZHH+j]);
            float n = tanhf(ih_s[2*ZHH+j] + r*hh_s[2*ZHH+j]);
            float hn = n + g*(hhat_s[j] - n);
            hhat_s[j] = hn;
            if (t == TT-1)
                out[(size_t)BB*TT*HH + (size_t)BB*HH + (size_t)b*ZHH + j] = hn;
        }
        __syncthreads();   // hhat_new visible

        // ===== z: 18 rows/wave, K=128 =====
        {
            float2 hv = *(const float2*)&hhat_s[lane*2];
            #pragma unroll 2
            for (int i = 0; i < 18; ++i) {
                int R = wv*18 + i;
                unsigned u = *(const unsigned*)(wbf + U_Z + (size_t)R*128 + lane*2);
                float p = wred(bflo(u)*hv.x + bfhi(u)*hv.y);
                if (lane == 0) {
                    float bias = (R < 96) ? zh_b[R] : ((R < 192) ? zx_b[R-96] : 0.f);
                    z_s[R] = p + bias;
                }
            }
        }
        __syncthreads();   // z ready

        // ===== d scales (9 dots K=32) + main gates -> h_new =====
        if (tid < HH) {
            const int h = tid;
            float dv[3][3];
            #pragma unroll
            for (int kind = 0; kind < 3; ++kind) {
                #pragma unroll
                for (int l = 0; l < 3; ++l) {
                    const uint4* w4 = (const uint4*)(wbf + U_D + ((size_t)((kind*3+l)*HH + h))*NZZ);
                    const float4* z4 = (const float4*)&z_s[kind*96 + l*32];
                    float acc = 0.f;
                    #pragma unroll
                    for (int j = 0; j < 4; ++j)
                        acc += dotbf8(w4[j], z4[2*j], z4[2*j+1]);
                    dv[kind][l] = acc;
                }
            }
            const float whh0 = whh_s[h], whh1 = whh_s[HH+h], whh2 = whh_s[2*HH+h];
            const float wxx0 = wxx_s[h], wxx1 = wxx_s[HH+h], wxx2 = wxx_s[2*HH+h];
            const float db0 = dv[2][0] + db_b[h];
            const float db1 = dv[2][1] + db_b[HH + h];
            const float db2 = dv[2][2] + db_b[2*HH + h];
            float r0 = sigmoidf_(dv[0][0]*whh0 + dv[1][0]*wxx0 + db0);
            float g0 = sigmoidf_(dv[0][1]*whh1 + dv[1][1]*wxx1 + db1);
            float n0 = tanhf  (r0*dv[0][2]*whh2 + dv[1][2]*wxx2 + db2);
            float hold = h_s[h];
            float hnew = n0 + g0*(hold - n0);
            h_s[h] = hnew;
            hbf_s[h] = f2bf(hnew);
            out[((size_t)b*TT + t)*HH + h] = hnew;
            if (t == TT-1) out[(size_t)BB*TT*HH + (size_t)b*HH + h] = hnew;
        }
        __syncthreads();   // h_s/hbf_s published

        // ===== step aligner (performance-only; no fences, no data exchange) =====
        // Keeps the 8 WGs per XCD sweeping the same 2.6 MB weight window so it
        // stays L2-resident. Correctness does not depend on this in any way.
        if (tid == 0) {
            __hip_atomic_fetch_add(&stepcnt[t], 1, __ATOMIC_RELAXED, __HIP_MEMORY_SCOPE_AGENT);
            while (__hip_atomic_load(&stepcnt[t], __ATOMIC_RELAXED, __HIP_MEMORY_SCOPE_AGENT) < BB)
                __builtin_amdgcn_s_sleep(2);
        }
        __syncthreads();
    }
}

// ---------- fp32 fallback (only if ws too small; never expected) ----------
__device__ __forceinline__ float dot4_(const float4 a, const float4 b) {
    return a.x*b.x + a.y*b.y + a.z*b.z + a.w*b.w;
}

__global__ __launch_bounds__(NT)
void hypercell_batch(
    const float* __restrict__ xs, const float* __restrict__ cond,
    const float* __restrict__ h_c, const float* __restrict__ h_c_hat,
    const float* __restrict__ x2h_w, const float* __restrict__ x2h_b,
    const float* __restrict__ h2h_w, const float* __restrict__ h2h_b,
    const float* __restrict__ zh_w, const float* __restrict__ zh_b,
    const float* __restrict__ zx_w, const float* __restrict__ zx_b,
    const float* __restrict__ zb_w,
    const float* __restrict__ dh_w, const float* __restrict__ dx_w,
    const float* __restrict__ db_w, const float* __restrict__ db_b,
    const float* __restrict__ wh, const float* __restrict__ wx,
    float* __restrict__ out)
{
    __shared__ float h_s[HH];
    __shared__ float hhat_s[ZHH];
    __shared__ float x_s[IN];
    __shared__ float cond_s[IN];
    __shared__ float whh_s[3*HH];
    __shared__ float wxx_s[3*HH];
    __shared__ float ih_s[3*ZHH];
    __shared__ float hh_s[3*ZHH];
    __shared__ float z_s[288];

    const int b    = blockIdx.x;
    const int tid  = threadIdx.x;
    const int lane = tid & 63;
    const int wv   = tid >> 6;

    if (tid < IN)  cond_s[tid] = cond[(size_t)b*IN + tid];
    if (tid < HH)  h_s[tid]    = h_c[(size_t)b*HH + tid];
    if (tid < ZHH) hhat_s[tid] = h_c_hat[(size_t)b*ZHH + tid];
    __syncthreads();

    for (int t = 0; t < TT; ++t) {
        if (tid < IN) x_s[tid] = xs[((size_t)b*TT + t)*IN + tid];
        const float4* h4 = (const float4*)h_s;
        const float4 ha = h4[lane];
        const float4 hb = h4[64 + lane];
        {
            const float* wl = wh + (size_t)(wv*96)*HH + lane*4;
            #pragma unroll 4
            for (int i = 0; i < 96; ++i) {
                float4 wa = *(const float4*)(wl + (size_t)i*HH);
                float4 wb = *(const float4*)(wl + (size_t)i*HH + 256);
                float p = wred(dot4_(wa, ha) + dot4_(wb, hb));
                if (lane == 0) whh_s[wv*96 + i] = p;
            }
        }
        {
            const float cv = cond_s[lane];
            const float* wbase = x2h_w + (size_t)(wv*24)*576;
            #pragma unroll 2
            for (int i = 0; i < 24; ++i) {
                const float* wr = wbase + (size_t)i*576;
                float4 wa = *(const float4*)(wr + lane*4);
                float4 wb = *(const float4*)(wr + 256 + lane*4);
                float  wc = wr[512 + lane];
                float p = wred(dot4_(wa, ha) + dot4_(wb, hb) + wc*cv);
                if (lane == 0) ih_s[wv*24 + i] = p + x2h_b[wv*24 + i];
            }
        }
        {
            const float2 hv = ((const float2*)hhat_s)[lane];
            const float* wbase = h2h_w + (size_t)(wv*24)*ZHH;
            #pragma unroll 4
            for (int i = 0; i < 24; ++i) {
                float2 w = *(const float2*)(wbase + (size_t)i*ZHH + lane*2);
                float p = wred(w.x*hv.x + w.y*hv.y);
                if (lane == 0) hh_s[wv*24 + i] = p + h2h_b[wv*24 + i];
            }
        }
        __syncthreads();
        {
            const float4* x4 = (const float4*)x_s;
            {
                const float4* wr = (const float4*)(wx + (size_t)tid*IN);
                float acc = 0.f;
                #pragma unroll
                for (int j = 0; j < 16; ++j) acc += dot4_(wr[j], x4[j]);
                wxx_s[tid] = acc;
            }
            if (tid < 512) {
                const int r = 1024 + tid;
                const float4* wr = (const float4*)(wx + (size_t)r*IN);
                float acc = 0.f;
                #pragma unroll
                for (int j = 0; j < 16; ++j) acc += dot4_(wr[j], x4[j]);
                wxx_s[r] = acc;
            }
        }
        if (tid < ZHH) {
            const int j = tid;
            float r = sigmoidf_(ih_s[j] + hh_s[j]);
            float g = sigmoidf_(ih_s[ZHH+j] + hh_s[ZHH+j]);
            float n = tanhf(ih_s[2*ZHH+j] + r*hh_s[2*ZHH+j]);
            float hn = n + g*(hhat_s[j] - n);
            hhat_s[j] = hn;
            if (t == TT-1)
                out[(size_t)BB*TT*HH + (size_t)BB*HH + (size_t)b*ZHH + j] = hn;
        }
        __syncthreads();
        {
            const float2 hv = ((const float2*)hhat_s)[lane];
            #pragma unroll 2
            for (int i = 0; i < 18; ++i) {
                const int R = wv*18 + i;
                const int kind = R / 96, r96 = R % 96;
                const float* wsrc = (kind == 0) ? zh_w : ((kind == 1) ? zx_w : zb_w);
                float2 w = *(const float2*)(wsrc + (size_t)r96*ZHH + lane*2);
                float p = wred(w.x*hv.x + w.y*hv.y);
                if (lane == 0) {
                    float bias = (kind == 0) ? zh_b[r96] : ((kind == 1) ? zx_b[r96] : 0.f);
                    z_s[R] = p + bias;
                }
            }
        }
        __syncthreads();
        if (tid < HH) {
            const int h = tid;
            const float* dsrc[3] = { dh_w, dx_w, db_w };
            float dv[3][3];
            #pragma unroll
            for (int kind = 0; kind < 3; ++kind) {
                #pragma unroll
                for (int l = 0; l < 3; ++l) {
                    const float4* wr = (const float4*)(dsrc[kind] + ((size_t)l*HH + h)*NZZ);
                    const float4* zp = (const float4*)&z_s[kind*96 + l*32];
                    float acc = 0.f;
                    #pragma unroll
                    for (int j = 0; j < 8; ++j) acc += dot4_(wr[j], zp[j]);
                    dv[kind][l] = acc;
                }
            }
            const float whh0 = whh_s[h], whh1 = whh_s[HH+h], whh2 = whh_s[2*HH+h];
            const float wxx0 = wxx_s[h], wxx1 = wxx_s[HH+h], wxx2 = wxx_s[2*HH+h];
            const float db0 = dv[2][0] + db_b[h];
            const float db1 = dv[2][1] + db_b[HH + h];
            const float db2 = dv[2][2] + db_b[2*HH + h];
            float r0 = sigmoidf_(dv[0][0]*whh0 + dv[1][0]*wxx0 + db0);
            float g0 = sigmoidf_(dv[0][1]*whh1 + dv[1][1]*wxx1 + db1);
            float n0 = tanhf  (r0*dv[0][2]*whh2 + dv[1][2]*wxx2 + db2);
            float hold = h_s[h];
            float hnew = n0 + g0*(hold - n0);
            h_s[h] = hnew;
            out[((size_t)b*TT + t)*HH + h] = hnew;
            if (t == TT-1) out[(size_t)BB*TT*HH + (size_t)b*HH + h] = hnew;
        }
        __syncthreads();
    }
}

extern "C" void kernel_launch(void* const* d_in, const int* in_sizes, int n_in,
                              void* d_out, int out_size, void* d_ws, size_t ws_size,
                              hipStream_t stream) {
    const float* xs      = (const float*)d_in[0];
    const float* cond    = (const float*)d_in[1];
    const float* h_c     = (const float*)d_in[2];
    const float* h_c_hat = (const float*)d_in[3];
    const float* x2h_w   = (const float*)d_in[4];
    const float* x2h_b   = (const float*)d_in[5];
    const float* h2h_w   = (const float*)d_in[6];
    const float* h2h_b   = (const float*)d_in[7];
    const float* zh_w    = (const float*)d_in[8];
    const float* zh_b    = (const float*)d_in[9];
    const float* zx_w    = (const float*)d_in[10];
    const float* zx_b    = (const float*)d_in[11];
    const float* zb_w    = (const float*)d_in[12];
    const float* dh_w    = (const float*)d_in[13];
    const float* dx_w    = (const float*)d_in[14];
    const float* db_w    = (const float*)d_in[15];
    const float* db_b    = (const float*)d_in[16];
    const float* wh      = (const float*)d_in[17];
    const float* wx      = (const float*)d_in[18];
    float* out = (float*)d_out;

    if (ws_size >= CNT_BYTES + TT * sizeof(int)) {
        unsigned short* wbf = (unsigned short*)d_ws;
        int* stepcnt = (int*)((char*)d_ws + CNT_BYTES);
        hipMemsetAsync(stepcnt, 0, TT * sizeof(int), stream);
        hipLaunchKernelGGL(conv_bf16, dim3((U_END + 255)/256), dim3(256), 0, stream,
                           wh, x2h_w, h2h_w, wx, zh_w, zx_w, zb_w, dh_w, dx_w, db_w, wbf);
        hipLaunchKernelGGL(hypercell_mfma, dim3(BB), dim3(NT), 0, stream,
                           xs, cond, h_c, h_c_hat, x2h_b, h2h_b, zh_b, zx_b, db_b,
                           wbf, stepcnt, out);
    } else {
        hipLaunchKernelGGL(hypercell_batch, dim3(BB), dim3(NT), 0, stream,
                           xs, cond, h_c, h_c_hat, x2h_w, x2h_b, h2h_w, h2h_b,
                           zh_w, zh_b, zx_w, zx_b, zb_w, dh_w, dx_w, db_w, db_b,
                           wh, wx, out);
    }
}

// Round 5
// 25691.232 us; speedup vs baseline: 2.5274x; 2.5274x over previous
//
#include <hip/hip_runtime.h>
#include <math.h>

// Problem constants
#define BB  64
#define TT  512
#define IN  64
#define HH  512
#define ZHH 128
#define NZZ 32
#define NWG 64
#define NT  1024

// ws byte offsets
#define WS_WHF   0u          // bf16 [64 wg][12288]  wh MFMA-frag slices
#define WS_X2H   1572864u    // bf16 [64 wg][6*576]  x2h row slices
#define WS_H32   2015232u    // f32  [64][512] h state
#define WS_HBF   2146304u    // bf16 [64][512] h state (bf16 mirror)
#define WS_IHHH  2211840u    // f32  [64][768] ih(384)||hh(384)
#define WS_Z     2408448u    // f32  [64][288]
#define WS_BAR   2482176u    // int bar; gen at +128B
#define WS_END   2482432u

typedef __attribute__((ext_vector_type(4))) float floatx4;
typedef __attribute__((ext_vector_type(8))) short shortx8;

__device__ __forceinline__ float sigmoidf_(float x) {
    return 1.0f / (1.0f + __expf(-x));
}
__device__ __forceinline__ float bflo(unsigned u) { return __uint_as_float(u << 16); }
__device__ __forceinline__ float bfhi(unsigned u) { return __uint_as_float(u & 0xffff0000u); }
__device__ __forceinline__ unsigned short f2bf(float f) {
    unsigned u = __float_as_uint(f);
    return (unsigned short)((u + 0x7fffu + ((u >> 16) & 1u)) >> 16);
}
// dot of 8 bf16 (weights) x 8 fp32 (acts)
__device__ __forceinline__ float dotbf8(uint4 U, float4 a, float4 b) {
    return bflo(U.x)*a.x + bfhi(U.x)*a.y + bflo(U.y)*a.z + bfhi(U.y)*a.w
         + bflo(U.z)*b.x + bfhi(U.z)*b.y + bflo(U.w)*b.z + bfhi(U.w)*b.w;
}
// dot of 8 bf16 x 8 bf16
__device__ __forceinline__ float dot8bb(uint4 W, uint4 H) {
    return bflo(W.x)*bflo(H.x) + bfhi(W.x)*bfhi(H.x)
         + bflo(W.y)*bflo(H.y) + bfhi(W.y)*bfhi(H.y)
         + bflo(W.z)*bflo(H.z) + bfhi(W.z)*bfhi(H.z)
         + bflo(W.w)*bflo(H.w) + bfhi(W.w)*bfhi(H.w);
}

// Device-wide barrier (R1-proven): counter + generation, agent scope.
__device__ __forceinline__ void gbar(int* bar, int* gen) {
    __syncthreads();
    if (threadIdx.x == 0) {
        __threadfence();
        int g = __hip_atomic_load(gen, __ATOMIC_RELAXED, __HIP_MEMORY_SCOPE_AGENT);
        int prev = __hip_atomic_fetch_add(bar, 1, __ATOMIC_RELAXED, __HIP_MEMORY_SCOPE_AGENT);
        if (prev == NWG - 1) {
            __hip_atomic_store(bar, 0, __ATOMIC_RELAXED, __HIP_MEMORY_SCOPE_AGENT);
            __hip_atomic_store(gen, g + 1, __ATOMIC_RELEASE, __HIP_MEMORY_SCOPE_AGENT);
        } else {
            while (__hip_atomic_load(gen, __ATOMIC_RELAXED, __HIP_MEMORY_SCOPE_AGENT) == g) {
                __builtin_amdgcn_s_sleep(2);
            }
        }
        __threadfence();
    }
    __syncthreads();
}

// ---------- pre-pass: pack wh (MFMA B-frag slices) + x2h row slices, bf16 ----------
__global__ __launch_bounds__(256)
void conv_pack(const float* __restrict__ wh, const float* __restrict__ x2h,
               unsigned short* __restrict__ whf_g, unsigned short* __restrict__ x2h_g)
{
    int i = blockIdx.x * 256 + threadIdx.x;
    if (i < 786432) {                       // wh frag: per WG 12288 elems
        int w = i / 12288, r = i % 12288;
        int g, hc, k;
        if (r < 8192) {                     // nb0: 16 rows (g0 x8, g1 x8)
            int k16 = r >> 9, quad = (r >> 7) & 3, s = (r >> 3) & 15, j = r & 7;
            g = s >> 3; hc = w*8 + (s & 7); k = k16*32 + quad*8 + j;
        } else {                            // nb1: 8 rows (g2), compact
            int r2 = r - 8192;
            int k16 = r2 >> 8, quad = (r2 >> 6) & 3, n8 = (r2 >> 3) & 7, j = r2 & 7;
            g = 2; hc = w*8 + n8; k = k16*32 + quad*8 + j;
        }
        whf_g[i] = f2bf(wh[((size_t)(g*512 + hc))*512 + k]);
    } else if (i < 1007616) {               // x2h slices: per WG 6*576
        int i2 = i - 786432;
        int w = i2 / 3456, r = i2 % 3456;
        int rr = r / 576, c = r % 576;
        x2h_g[i2] = f2bf(x2h[(size_t)(w*6 + rr)*576 + c]);
    }
}

// ---------- main: 64 persistent WGs, LDS-resident weight slices, 3 barriers/step ----
__global__ __launch_bounds__(NT)
void hypercell_slices(
    const float* __restrict__ xs, const float* __restrict__ cond,
    const float* __restrict__ h_c, const float* __restrict__ h_c_hat,
    const float* __restrict__ x2h_b, const float* __restrict__ h2h_b,
    const float* __restrict__ h2h_w,
    const float* __restrict__ zh_w, const float* __restrict__ zh_b,
    const float* __restrict__ zx_w, const float* __restrict__ zx_b,
    const float* __restrict__ zb_w,
    const float* __restrict__ dh_w, const float* __restrict__ dx_w,
    const float* __restrict__ db_w, const float* __restrict__ db_b,
    const float* __restrict__ wx,
    char* __restrict__ wsb, float* __restrict__ out)
{
    __shared__ __align__(16) unsigned short whf_s[12288];  // 24.6 KB
    __shared__ __align__(16) unsigned short x2hs[6*576];   // 6.9 KB
    __shared__ float wx_s[24*64];    // 6 KB   rows (g,hc) of Gw
    __shared__ float h2h_s[6*128];   // 3 KB
    __shared__ float zw_s[5*128];    // 2.5 KB
    __shared__ float zb_s[8];
    __shared__ float dw_s[72*32];    // 9.2 KB  [kl*8+hc][32]
    __shared__ float x_s[64*64];     // 16 KB
    __shared__ float hhat_s[64*128]; // 32 KB (local full copy, fp32)
    __shared__ float whh_l[64*24];   // 6 KB [b][g*8+hc]
    __shared__ float wxx_l[64*24];   // 6 KB
    __shared__ float d_l[64*72];     // 18 KB [b][kl*8+hc]
    __shared__ float ihp_s[384*2];   // 3 KB ih partials

    const int w    = blockIdx.x;
    const int tid  = threadIdx.x;
    const int lane = tid & 63;
    const int wv   = tid >> 6;
    const int zcnt  = (w < 32) ? 5 : 4;
    const int zbase = (w < 32) ? w*5 : 160 + (w - 32)*4;

    unsigned short* whf_g = (unsigned short*)(wsb + WS_WHF) + (size_t)w*12288;
    unsigned short* x2h_g = (unsigned short*)(wsb + WS_X2H) + (size_t)w*3456;
    float* h32g  = (float*)(wsb + WS_H32);
    unsigned short* hbfg = (unsigned short*)(wsb + WS_HBF);
    float* ihhhg = (float*)(wsb + WS_IHHH);
    float* zg    = (float*)(wsb + WS_Z);
    int* bar = (int*)(wsb + WS_BAR);
    int* gen = bar + 32;

    // ---------- init: stage weight slices into LDS, init states ----------
    for (int i = tid; i < 1536; i += NT)           // whf: 12288 elems = 1536 uint4
        ((uint4*)whf_s)[i] = ((const uint4*)whf_g)[i];
    for (int i = tid; i < 432; i += NT)            // x2h slice: 3456 = 432 uint4
        ((uint4*)x2hs)[i] = ((const uint4*)x2h_g)[i];
    for (int i = tid; i < 1536; i += NT) {         // wx rows (g,hc)
        int rc = i >> 6, c = i & 63;
        int g = rc >> 3, hc = w*8 + (rc & 7);
        wx_s[i] = wx[((size_t)(g*512 + hc))*64 + c];
    }
    for (int i = tid; i < 768; i += NT) {          // h2h rows
        int rr = i >> 7, c = i & 127;
        h2h_s[i] = h2h_w[(size_t)(w*6 + rr)*128 + c];
    }
    for (int i = tid; i < zcnt*128; i += NT) {     // z rows
        int rr = i >> 7, c = i & 127;
        int R = zbase + rr, kind = R / 96, r96 = R % 96;
        const float* src = (kind == 0) ? zh_w : ((kind == 1) ? zx_w : zb_w);
        zw_s[i] = src[(size_t)r96*128 + c];
    }
    if (tid < zcnt) {
        int R = zbase + tid;
        zb_s[tid] = (R < 96) ? zh_b[R] : ((R < 192) ? zx_b[R - 96] : 0.f);
    }
    for (int i = tid; i < 2304; i += NT) {         // d rows
        int u = i >> 5, c = i & 31;
        int kl = u >> 3, hc = w*8 + (u & 7);
        int kind = kl / 3, l = kl % 3;
        const float* src = (kind == 0) ? dh_w : ((kind == 1) ? dx_w : db_w);
        dw_s[i] = src[((size_t)(l*512) + hc)*32 + c];
    }
    for (int i = tid; i < 8192; i += NT) hhat_s[i] = h_c_hat[i];
    {   // x_0
        int b = tid >> 4, c4 = tid & 15;
        ((float4*)x_s)[tid] = *(const float4*)&xs[((size_t)b*TT + 0)*IN + c4*4];
    }
    if (tid < 512) {                               // h state slice
        int idx = w*512 + tid;
        float v = h_c[idx];
        h32g[idx] = v; hbfg[idx] = f2bf(v);
    }
    gbar(bar, gen);

    for (int t = 0; t < TT; ++t) {
        // ================= P1: whh (MFMA) + ih/hh rows + wxx =================
        if (wv < 4) {
            // waves 0-3: whh for 16 batches each, rows (3 gates x 8 hc)
            const int mb = wv, s = lane & 15, quad = lane >> 4;
            floatx4 acc0 = {0.f,0.f,0.f,0.f}, acc1 = {0.f,0.f,0.f,0.f};
            const unsigned short* hb = hbfg + (size_t)(mb*16 + s)*512 + quad*8;
            #pragma unroll 4
            for (int k16 = 0; k16 < 16; ++k16) {
                shortx8 aF = *(const shortx8*)(hb + k16*32);
                shortx8 b0 = *(const shortx8*)&whf_s[((k16*4 + quad)*16 + s)*8];
                shortx8 b1 = *(const shortx8*)&whf_s[8192 + ((k16*4 + quad)*8 + (lane & 7))*8];
                acc0 = __builtin_amdgcn_mfma_f32_16x16x32_bf16(aF, b0, acc0, 0, 0, 0);
                acc1 = __builtin_amdgcn_mfma_f32_16x16x32_bf16(aF, b1, acc1, 0, 0, 0);
            }
            #pragma unroll
            for (int r = 0; r < 4; ++r) {
                int b = mb*16 + quad*4 + r;
                whh_l[b*24 + (s >> 3)*8 + (s & 7)] = acc0[r];
                if (s < 8) whh_l[b*24 + 16 + s] = acc1[r];
            }
        } else {
            int t2 = tid - 256;                    // 0..767
            {   // ih partials: 2 threads per dot (384 dots, K=512 split + cond)
                int d = t2 >> 1, half = t2 & 1;
                int b = d / 6, rr = d % 6;
                const uint4* hb = (const uint4*)(hbfg + (size_t)b*512);
                const uint4* wr = (const uint4*)&x2hs[rr*576];
                float acc = 0.f;
                if (half == 0) {
                    #pragma unroll 8
                    for (int c8 = 0; c8 < 32; ++c8) acc += dot8bb(wr[c8], hb[c8]);
                } else {
                    #pragma unroll 8
                    for (int c8 = 32; c8 < 64; ++c8) acc += dot8bb(wr[c8], hb[c8]);
                    const float4* cv = (const float4*)(cond + (size_t)b*IN);
                    const uint4* wc = (const uint4*)&x2hs[rr*576 + 512];
                    #pragma unroll
                    for (int c8 = 0; c8 < 8; ++c8)
                        acc += dotbf8(wc[c8], cv[2*c8], cv[2*c8+1]);
                }
                ihp_s[d*2 + half] = acc;
            }
            {   // wxx: 1536 dots K=64, 2 per thread (fp32)
                #pragma unroll
                for (int ii = 0; ii < 2; ++ii) {
                    int u = t2*2 + ii;
                    int b = u / 24, rc = u % 24;
                    const float4* xv = (const float4*)&x_s[b*64];
                    const float4* wv4 = (const float4*)&wx_s[rc*64];
                    float acc = 0.f;
                    #pragma unroll
                    for (int c4 = 0; c4 < 16; ++c4)
                        acc += xv[c4].x*wv4[c4].x + xv[c4].y*wv4[c4].y
                             + xv[c4].z*wv4[c4].z + xv[c4].w*wv4[c4].w;
                    wxx_l[b*24 + rc] = acc;
                }
            }
        }
        __syncthreads();
        if (tid < 384) {                           // finalize ih + hh, publish
            int b = tid / 6, rr = tid % 6, j = w*6 + rr;
            float ihv = ihp_s[tid*2] + ihp_s[tid*2 + 1] + x2h_b[j];
            const float* hv = &hhat_s[b*128];
            const float* wr = &h2h_s[rr*128];
            float hh = h2h_b[j];
            #pragma unroll 8
            for (int c = 0; c < 128; ++c) hh += hv[c]*wr[c];
            ihhhg[(size_t)b*768 + j] = ihv;
            ihhhg[(size_t)b*768 + 384 + j] = hh;
        }
        gbar(bar, gen);

        // ================= P2: hhat (redundant, local) + z slices =================
        #pragma unroll
        for (int i = 0; i < 8; ++i) {
            int u = tid + i*NT;                    // (b,j) unit
            int b = u >> 7, j = u & 127;
            const float* p = ihhhg + (size_t)b*768;
            float i_r = p[j], i_i = p[128 + j], i_n = p[256 + j];
            float h_r = p[384 + j], h_i = p[512 + j], h_n = p[640 + j];
            float r = sigmoidf_(i_r + h_r);
            float g = sigmoidf_(i_i + h_i);
            float n = tanhf(i_n + r*h_n);
            int idx = b*128 + j;
            float hn = n + g*(hhat_s[idx] - n);
            hhat_s[idx] = hn;
            if (t == TT-1 && w == 0)
                out[(size_t)BB*TT*HH + (size_t)BB*HH + (size_t)b*128 + j] = hn;
        }
        __syncthreads();
        if (tid < 64*zcnt) {                       // z rows
            int b = tid / zcnt, rr = tid % zcnt;
            const float* hv = &hhat_s[b*128];
            const float* wr = &zw_s[rr*128];
            float acc = zb_s[rr];
            #pragma unroll 8
            for (int c = 0; c < 128; ++c) acc += hv[c]*wr[c];
            zg[(size_t)b*288 + zbase + rr] = acc;
        }
        gbar(bar, gen);

        // ================= P3: d slices + gates -> h_new =================
        if (t + 1 < TT) {                          // stage x_{t+1}
            int b = tid >> 4, c4 = tid & 15;
            ((float4*)x_s)[tid] = *(const float4*)&xs[((size_t)b*TT + t + 1)*IN + c4*4];
        }
        #pragma unroll
        for (int i = 0; i < 5; ++i) {
            int idx = tid + i*NT;
            if (idx < 4608) {
                int b = idx / 72, u = idx % 72, kl = u >> 3;
                const float4* zp = (const float4*)(zg + (size_t)b*288 + kl*32);
                const float4* wr = (const float4*)&dw_s[u*32];
                float acc = 0.f;
                #pragma unroll
                for (int c4 = 0; c4 < 8; ++c4)
                    acc += zp[c4].x*wr[c4].x + zp[c4].y*wr[c4].y
                         + zp[c4].z*wr[c4].z + zp[c4].w*wr[c4].w;
                d_l[b*72 + u] = acc;
            }
        }
        __syncthreads();
        if (tid < 512) {
            int b = tid >> 3, hc = tid & 7, h = w*8 + hc;
            float whh0 = whh_l[b*24 + hc], whh1 = whh_l[b*24 + 8 + hc], whh2 = whh_l[b*24 + 16 + hc];
            float wxx0 = wxx_l[b*24 + hc], wxx1 = wxx_l[b*24 + 8 + hc], wxx2 = wxx_l[b*24 + 16 + hc];
            const float* dp = &d_l[b*72];
            float db0 = dp[(0*3 + 0)*8 + hc]*0.f; // placeholder (overwritten below)
            float dh0 = dp[(0*3+0)*8+hc], dh1 = dp[(0*3+1)*8+hc], dh2 = dp[(0*3+2)*8+hc];
            float dx0 = dp[(1*3+0)*8+hc], dx1 = dp[(1*3+1)*8+hc], dx2 = dp[(1*3+2)*8+hc];
            float dbv0 = dp[(2*3+0)*8+hc] + db_b[h];
            float dbv1 = dp[(2*3+1)*8+hc] + db_b[512 + h];
            float dbv2 = dp[(2*3+2)*8+hc] + db_b[1024 + h];
            (void)db0;
            float r0 = sigmoidf_(dh0*whh0 + dx0*wxx0 + dbv0);
            float g0 = sigmoidf_(dh1*whh1 + dx1*wxx1 + dbv1);
            float n0 = tanhf(r0*dh2*whh2 + dx2*wxx2 + dbv2);
            float hold = h32g[(size_t)b*512 + h];
            float hnew = n0 + g0*(hold - n0);
            h32g[(size_t)b*512 + h] = hnew;
            hbfg[(size_t)b*512 + h] = f2bf(hnew);
            out[((size_t)b*TT + t)*HH + h] = hnew;
            if (t == TT-1) out[(size_t)BB*TT*HH + (size_t)b*512 + h] = hnew;
        }
        gbar(bar, gen);
    }
}

// ---------- fp32 fallback (R2 kernel; used only if ws too small) ----------
__device__ __forceinline__ float dot4_(const float4 a, const float4 b) {
    return a.x*b.x + a.y*b.y + a.z*b.z + a.w*b.w;
}
__device__ __forceinline__ float wred(float v) {
    v += __shfl_xor(v, 32, 64); v += __shfl_xor(v, 16, 64); v += __shfl_xor(v, 8, 64);
    v += __shfl_xor(v, 4, 64);  v += __shfl_xor(v, 2, 64);  v += __shfl_xor(v, 1, 64);
    return v;
}
__global__ __launch_bounds__(NT)
void hypercell_batch(
    const float* __restrict__ xs, const float* __restrict__ cond,
    const float* __restrict__ h_c, const float* __restrict__ h_c_hat,
    const float* __restrict__ x2h_w, const float* __restrict__ x2h_b,
    const float* __restrict__ h2h_w, const float* __restrict__ h2h_b,
    const float* __restrict__ zh_w, const float* __restrict__ zh_b,
    const float* __restrict__ zx_w, const float* __restrict__ zx_b,
    const float* __restrict__ zb_w,
    const float* __restrict__ dh_w, const float* __restrict__ dx_w,
    const float* __restrict__ db_w, const float* __restrict__ db_b,
    const float* __restrict__ wh, const float* __restrict__ wx,
    float* __restrict__ out)
{
    __shared__ float h_s[HH];
    __shared__ float hhat_s[ZHH];
    __shared__ float x_s[IN];
    __shared__ float cond_s[IN];
    __shared__ float whh_s[3*HH];
    __shared__ float wxx_s[3*HH];
    __shared__ float ih_s[3*ZHH];
    __shared__ float hh_s[3*ZHH];
    __shared__ float z_s[288];
    const int b = blockIdx.x, tid = threadIdx.x, lane = tid & 63, wv = tid >> 6;
    if (tid < IN)  cond_s[tid] = cond[(size_t)b*IN + tid];
    if (tid < HH)  h_s[tid]    = h_c[(size_t)b*HH + tid];
    if (tid < ZHH) hhat_s[tid] = h_c_hat[(size_t)b*ZHH + tid];
    __syncthreads();
    for (int t = 0; t < TT; ++t) {
        if (tid < IN) x_s[tid] = xs[((size_t)b*TT + t)*IN + tid];
        const float4* h4 = (const float4*)h_s;
        const float4 ha = h4[lane]; const float4 hb = h4[64 + lane];
        {
            const float* wl = wh + (size_t)(wv*96)*HH + lane*4;
            #pragma unroll 4
            for (int i = 0; i < 96; ++i) {
                float p = wred(dot4_(*(const float4*)(wl + (size_t)i*HH), ha)
                             + dot4_(*(const float4*)(wl + (size_t)i*HH + 256), hb));
                if (lane == 0) whh_s[wv*96 + i] = p;
            }
        }
        {
            const float cv = cond_s[lane];
            const float* wbase = x2h_w + (size_t)(wv*24)*576;
            #pragma unroll 2
            for (int i = 0; i < 24; ++i) {
                const float* wr = wbase + (size_t)i*576;
                float p = wred(dot4_(*(const float4*)(wr + lane*4), ha)
                             + dot4_(*(const float4*)(wr + 256 + lane*4), hb) + wr[512 + lane]*cv);
                if (lane == 0) ih_s[wv*24 + i] = p + x2h_b[wv*24 + i];
            }
        }
        {
            const float2 hv = ((const float2*)hhat_s)[lane];
            const float* wbase = h2h_w + (size_t)(wv*24)*ZHH;
            #pragma unroll 4
            for (int i = 0; i < 24; ++i) {
                float2 wq = *(const float2*)(wbase + (size_t)i*ZHH + lane*2);
                float p = wred(wq.x*hv.x + wq.y*hv.y);
                if (lane == 0) hh_s[wv*24 + i] = p + h2h_b[wv*24 + i];
            }
        }
        __syncthreads();
        {
            const float4* x4 = (const float4*)x_s;
            {
                const float4* wr = (const float4*)(wx + (size_t)tid*IN);
                float acc = 0.f;
                #pragma unroll
                for (int j = 0; j < 16; ++j) acc += dot4_(wr[j], x4[j]);
                wxx_s[tid] = acc;
            }
            if (tid < 512) {
                const int r = 1024 + tid;
                const float4* wr = (const float4*)(wx + (size_t)r*IN);
                float acc = 0.f;
                #pragma unroll
                for (int j = 0; j < 16; ++j) acc += dot4_(wr[j], x4[j]);
                wxx_s[r] = acc;
            }
        }
        if (tid < ZHH) {
            const int j = tid;
            float r = sigmoidf_(ih_s[j] + hh_s[j]);
            float g = sigmoidf_(ih_s[ZHH+j] + hh_s[ZHH+j]);
            float n = tanhf(ih_s[2*ZHH+j] + r*hh_s[2*ZHH+j]);
            float hn = n + g*(hhat_s[j] - n);
            hhat_s[j] = hn;
            if (t == TT-1)
                out[(size_t)BB*TT*HH + (size_t)BB*HH + (size_t)b*ZHH + j] = hn;
        }
        __syncthreads();
        {
            const float2 hv = ((const float2*)hhat_s)[lane];
            #pragma unroll 2
            for (int i = 0; i < 18; ++i) {
                const int R = wv*18 + i, kind = R / 96, r96 = R % 96;
                const float* wsrc = (kind == 0) ? zh_w : ((kind == 1) ? zx_w : zb_w);
                float2 wq = *(const float2*)(wsrc + (size_t)r96*ZHH + lane*2);
                float p = wred(wq.x*hv.x + wq.y*hv.y);
                if (lane == 0)
                    z_s[R] = p + ((kind == 0) ? zh_b[r96] : ((kind == 1) ? zx_b[r96] : 0.f));
            }
        }
        __syncthreads();
        if (tid < HH) {
            const int h = tid;
            const float* dsrc[3] = { dh_w, dx_w, db_w };
            float dv[3][3];
            #pragma unroll
            for (int kind = 0; kind < 3; ++kind)
                #pragma unroll
                for (int l = 0; l < 3; ++l) {
                    const float4* wr = (const float4*)(dsrc[kind] + ((size_t)l*HH + h)*NZZ);
                    const float4* zp = (const float4*)&z_s[kind*96 + l*32];
                    float acc = 0.f;
                    #pragma unroll
                    for (int j = 0; j < 8; ++j) acc += dot4_(wr[j], zp[j]);
                    dv[kind][l] = acc;
                }
            float whh0 = whh_s[h], whh1 = whh_s[HH+h], whh2 = whh_s[2*HH+h];
            float wxx0 = wxx_s[h], wxx1 = wxx_s[HH+h], wxx2 = wxx_s[2*HH+h];
            float db0 = dv[2][0] + db_b[h], db1 = dv[2][1] + db_b[HH+h], db2 = dv[2][2] + db_b[2*HH+h];
            float r0 = sigmoidf_(dv[0][0]*whh0 + dv[1][0]*wxx0 + db0);
            float g0 = sigmoidf_(dv[0][1]*whh1 + dv[1][1]*wxx1 + db1);
            float n0 = tanhf(r0*dv[0][2]*whh2 + dv[1][2]*wxx2 + db2);
            float hold = h_s[h];
            float hnew = n0 + g0*(hold - n0);
            h_s[h] = hnew;
            out[((size_t)b*TT + t)*HH + h] = hnew;
            if (t == TT-1) out[(size_t)BB*TT*HH + (size_t)b*HH + h] = hnew;
        }
        __syncthreads();
    }
}

extern "C" void kernel_launch(void* const* d_in, const int* in_sizes, int n_in,
                              void* d_out, int out_size, void* d_ws, size_t ws_size,
                              hipStream_t stream) {
    const float* xs      = (const float*)d_in[0];
    const float* cond    = (const float*)d_in[1];
    const float* h_c     = (const float*)d_in[2];
    const float* h_c_hat = (const float*)d_in[3];
    const float* x2h_w   = (const float*)d_in[4];
    const float* x2h_b   = (const float*)d_in[5];
    const float* h2h_w   = (const float*)d_in[6];
    const float* h2h_b   = (const float*)d_in[7];
    const float* zh_w    = (const float*)d_in[8];
    const float* zh_b    = (const float*)d_in[9];
    const float* zx_w    = (const float*)d_in[10];
    const float* zx_b    = (const float*)d_in[11];
    const float* zb_w    = (const float*)d_in[12];
    const float* dh_w    = (const float*)d_in[13];
    const float* dx_w    = (const float*)d_in[14];
    const float* db_w    = (const float*)d_in[15];
    const float* db_b    = (const float*)d_in[16];
    const float* wh      = (const float*)d_in[17];
    const float* wx      = (const float*)d_in[18];
    float* out = (float*)d_out;

    if (ws_size >= (size_t)WS_END) {
        char* wsb = (char*)d_ws;
        hipMemsetAsync(wsb + WS_BAR, 0, 256, stream);
        hipLaunchKernelGGL(conv_pack, dim3(3936), dim3(256), 0, stream,
                           wh, x2h_w,
                           (unsigned short*)(wsb + WS_WHF),
                           (unsigned short*)(wsb + WS_X2H));
        hipLaunchKernelGGL(hypercell_slices, dim3(NWG), dim3(NT), 0, stream,
                           xs, cond, h_c, h_c_hat, x2h_b, h2h_b, h2h_w,
                           zh_w, zh_b, zx_w, zx_b, zb_w,
                           dh_w, dx_w, db_w, db_b, wx, wsb, out);
    } else {
        hipLaunchKernelGGL(hypercell_batch, dim3(BB), dim3(NT), 0, stream,
                           xs, cond, h_c, h_c_hat, x2h_w, x2h_b, h2h_w, h2h_b,
                           zh_w, zh_b, zx_w, zx_b, zb_w, dh_w, dx_w, db_w, db_b,
                           wh, wx, out);
    }
}